// Round 10
// baseline (546.564 us; speedup 1.0000x reference)
//
#include <hip/hip_runtime.h>
#include <hip/hip_bf16.h>
#include <math.h>

#define N_TOK   16384
#define D_IN    1024
#define D_MODEL 1024
#define HID     256
#define NEXP    10
#define D_OUT   1024

// Expert routing: pad each expert's list to a multiple of EPAD so every
// row tile is single-expert. Static capacity => static grid (graph-safe).
#define EPAD 128
#define A_CAP (2*N_TOK + NEXP*EPAD)   // 34048 = 532 * 64

typedef __attribute__((ext_vector_type(8))) __bf16 bf16x8;
typedef __attribute__((ext_vector_type(4))) float floatx4;

// ---------------------------------------------------------------------------
// XCD-chunked block swizzle (bijective): R8 confirmed — FETCH 290MB -> 77MB
// (~ideal). Keep on all MFMA kernels.
// ---------------------------------------------------------------------------
__device__ __forceinline__ int xcd_chunk(int orig, int nwg)
{
    const int q = nwg >> 3, r = nwg & 7;
    const int c = orig & 7, j = orig >> 3;
    return (c < r ? c * (q + 1) : r * (q + 1) + (c - r) * q) + j;
}

// ---------------------------------------------------------------------------
// LDS tile layout (row = 64 shorts = 8 chunks of 16B): source chunk c of row r
// is stored at position c ^ (r&7); staging applies the inverse swizzle on the
// per-lane source address so the LDS store is rowgroup_base + lane*16B.
// ---------------------------------------------------------------------------
__device__ __forceinline__ bf16x8 lds_frag(const short* base, int row, int chunk)
{
    return *(const bf16x8*)(base + row * 64 + (chunk << 3));
}

// plain bf16: tile covers K-step 64 (chunks 0..7 = k 0..63)
__device__ __forceinline__ void tile_plain(const short* As, const short* Bs,
                                           int wm, int wn, int lane, floatx4 acc[4][4])
{
    const int m15 = lane & 15, quad = lane >> 4, sw = m15 & 7;
#pragma unroll
    for (int kk = 0; kk < 2; ++kk) {
        bf16x8 af[4], bfr[4];
#pragma unroll
        for (int i = 0; i < 4; ++i)
            af[i] = lds_frag(As, wm * 64 + i * 16 + m15, ((kk << 2) + quad) ^ sw);
#pragma unroll
        for (int j = 0; j < 4; ++j)
            bfr[j] = lds_frag(Bs, wn * 64 + j * 16 + m15, ((kk << 2) + quad) ^ sw);
#pragma unroll
        for (int i = 0; i < 4; ++i)
#pragma unroll
            for (int j = 0; j < 4; ++j)
                acc[i][j] = __builtin_amdgcn_mfma_f32_16x16x32_bf16(af[i], bfr[j],
                                                                    acc[i][j], 0, 0, 0);
    }
}

// split bf16 (3-term): K-step 32; chunks 0..3 = hi, 4..7 = lo.
// acc += Ah*Bh + Ah*Bl + Al*Bh  (Al*Bl ~ 2^-18, dropped)
__device__ __forceinline__ void tile_split(const short* As, const short* Bs,
                                           int wm, int wn, int lane, floatx4 acc[4][4])
{
    const int m15 = lane & 15, quad = lane >> 4, sw = m15 & 7;
    bf16x8 ah[4], al[4], bh[4], bl[4];
#pragma unroll
    for (int i = 0; i < 4; ++i) {
        int r = wm * 64 + i * 16 + m15;
        ah[i] = lds_frag(As, r, quad ^ sw);
        al[i] = lds_frag(As, r, (4 + quad) ^ sw);
    }
#pragma unroll
    for (int j = 0; j < 4; ++j) {
        int r = wn * 64 + j * 16 + m15;
        bh[j] = lds_frag(Bs, r, quad ^ sw);
        bl[j] = lds_frag(Bs, r, (4 + quad) ^ sw);
    }
#pragma unroll
    for (int i = 0; i < 4; ++i)
#pragma unroll
        for (int j = 0; j < 4; ++j) {
            floatx4 c = acc[i][j];
            c = __builtin_amdgcn_mfma_f32_16x16x32_bf16(ah[i], bh[j], c, 0, 0, 0);
            c = __builtin_amdgcn_mfma_f32_16x16x32_bf16(ah[i], bl[j], c, 0, 0, 0);
            c = __builtin_amdgcn_mfma_f32_16x16x32_bf16(al[i], bh[j], c, 0, 0, 0);
            acc[i][j] = c;
        }
}

// ---------------------------------------------------------------------------
// Split-bf16 GEMM: C = A @ Bt^T + bias, hi/lo planes; z-batched via strides.
// Weight products only (small grids).
// ---------------------------------------------------------------------------
__global__ __launch_bounds__(256)
void gemm_split_kernel(const __hip_bfloat16* Ahi_, const __hip_bfloat16* Alo_,
                       const __hip_bfloat16* Bhi_, const __hip_bfloat16* Blo_,
                       const float* __restrict__ bias,
                       __hip_bfloat16* Chi_, __hip_bfloat16* Clo_, int K, int N,
                       size_t zsA, size_t zsB, size_t zsC)
{
    __shared__ __align__(16) short As[128 * 64];
    __shared__ __align__(16) short Bs[128 * 64];
    const short* Ahi = (const short*)Ahi_;
    const short* Alo = (const short*)Alo_;
    const short* Bhi = (const short*)Bhi_;
    const short* Blo = (const short*)Blo_;

    const int tid = threadIdx.x, lane = tid & 63, w = tid >> 6;
    const int wm = w & 1, wn = w >> 1;
    const size_t zA = (size_t)blockIdx.z * zsA;
    const size_t zB = (size_t)blockIdx.z * zsB;
    const size_t zC = (size_t)blockIdx.z * zsC;
    const int lin = blockIdx.y * gridDim.x + blockIdx.x;
    const int lgc = xcd_chunk(lin, gridDim.x * gridDim.y);
    const int row0 = (lgc / gridDim.x) * 128, col0 = (lgc % gridDim.x) * 128;
    const int lr = lane >> 3;
    const int g = (lane & 7) ^ lr;
    const int plane = g >> 2, colel = (g & 3) * 8;

    const short* pA[4];
    const short* pB[4];
#pragma unroll
    for (int i = 0; i < 4; ++i) {
        int r = w * 32 + i * 8 + lr;
        pA[i] = (plane ? Alo : Ahi) + zA + (size_t)(row0 + r) * K + colel;
        pB[i] = (plane ? Blo : Bhi) + zB + (size_t)(col0 + r) * K + colel;
    }

    floatx4 acc[4][4];
#pragma unroll
    for (int i = 0; i < 4; ++i)
#pragma unroll
        for (int j = 0; j < 4; ++j) acc[i][j] = (floatx4)(0.f);

    bf16x8 va[4], vb[4];
#pragma unroll
    for (int i = 0; i < 4; ++i) {
        va[i] = *(const bf16x8*)(pA[i]);
        vb[i] = *(const bf16x8*)(pB[i]);
    }

    for (int k0 = 0; k0 < K; k0 += 32) {
        __syncthreads();
#pragma unroll
        for (int i = 0; i < 4; ++i) {
            *(bf16x8*)(&As[(w * 32 + i * 8) * 64 + lane * 8]) = va[i];
            *(bf16x8*)(&Bs[(w * 32 + i * 8) * 64 + lane * 8]) = vb[i];
        }
        __syncthreads();
        if (k0 + 32 < K) {
#pragma unroll
            for (int i = 0; i < 4; ++i) {
                va[i] = *(const bf16x8*)(pA[i] + k0 + 32);
                vb[i] = *(const bf16x8*)(pB[i] + k0 + 32);
            }
        }
        tile_split(As, Bs, wm, wn, lane, acc);
    }

    const int m15 = lane & 15, quad = lane >> 4;
#pragma unroll
    for (int i = 0; i < 4; ++i) {
#pragma unroll
        for (int t = 0; t < 4; ++t) {
            int row = row0 + wm * 64 + i * 16 + quad * 4 + t;
            size_t rb = zC + (size_t)row * N;
#pragma unroll
            for (int j = 0; j < 4; ++j) {
                int col = col0 + wn * 64 + j * 16 + m15;
                float v = acc[i][j][t] + bias[col];
                __hip_bfloat16 hi = __float2bfloat16(v);
                Chi_[rb + col] = hi;
                if (Clo_) Clo_[rb + col] = __float2bfloat16(v - __bfloat162float(hi));
            }
        }
    }
}

// ---------------------------------------------------------------------------
// R13 FUSED expert kernel: one block = 64 slots, BOTH layers.
//   phase 1: hid[64][256] = relu(x[tok]@W1eff[e] + b1eff[e])   (2-term split;
//            x gathered as fp32 and converted hi/lo in-register — bit-identical
//            to the old convert_gate planes; x planes no longer materialized)
//   phase 2: exp_out[64][1024] = hid @ W2t[e]^T with hid RESIDENT IN LDS
//            (no hid HBM round-trip, no expert2 launch).
// Rationale (R12 null): expert1 was bound by per-K-step barrier/staging
// overhead over few MFMA; phase-1 here doubles MFMA per barrier-pair (full
// 256-col hid), phase-2 amortizes the same A across 8 col-chunks.
// LDS: As 8KB + Bs 32KB + Hs 32KB = 72KB (2 blocks/CU).
// ---------------------------------------------------------------------------
__global__ __launch_bounds__(256)
void expert_fused_kernel(const float* __restrict__ x, const float* __restrict__ fzero,
                         const __hip_bfloat16* W1e_hi_, const float* __restrict__ b1eff,
                         const __hip_bfloat16* W2t_,
                         const int* __restrict__ assign_token, const int* __restrict__ offs,
                         __hip_bfloat16* exp_out_)
{
    __shared__ __align__(16) short As[64 * 64];       // phase-1 A (hi|lo of 32 k)
    __shared__ __align__(16) short Bs[2][128 * 64];   // phase-1 B (hi; inert half)
    __shared__ __align__(16) short Hs[4][64 * 64];    // hid, 4 k-tiles of 64

    const int tid = threadIdx.x, lane = tid & 63, w = tid >> 6;
    const int lgc = xcd_chunk(blockIdx.x, gridDim.x);
    const int row0 = lgc * 64;
    const int lr = lane >> 3;
    const int g = (lane & 7) ^ lr;          // swizzled source chunk
    const int plane = g >> 2, kofs = (g & 3) * 8;
    const int m15 = lane & 15, quad = lane >> 4, sw = m15 & 7;

    int e = NEXP - 1;
    for (int q = 0; q < NEXP; ++q) { if (row0 < offs[q + 1]) { e = q; break; } }
    const short* Bh = (const short*)W1e_hi_ + (size_t)e * HID * D_IN;
    const short* W2 = (const short*)W2t_ + (size_t)e * D_OUT * HID;

    // ---------------- phase 1 ----------------
    // A source: fp32 token rows (both planes read the same 8 floats; plane=0
    // stages hi=cvt(f), plane=1 stages lo=cvt(f-hi) — identical math to the
    // old convert kernel -> bit-identical planes).
    const float* pX[2];
#pragma unroll
    for (int i = 0; i < 2; ++i) {
        int r = w * 16 + i * 8 + lr;
        int tok = assign_token[row0 + r];
        pX[i] = (tok >= 0 ? x + (size_t)tok * D_IN : fzero) + kofs;
    }
    // B: 256 rows of W1eff[e] as two 128-row tiles.
    const short* pB[8];
#pragma unroll
    for (int i = 0; i < 8; ++i) {
        int r = w * 32 + (i & 3) * 8 + lr + (i >= 4 ? 128 : 0);
        pB[i] = Bh + (size_t)r * D_IN + kofs;
    }

    floatx4 acc1[4][4];
#pragma unroll
    for (int i = 0; i < 4; ++i)
#pragma unroll
        for (int j = 0; j < 4; ++j) acc1[i][j] = (floatx4)(0.f);

    float4 fa[2][2];
    bf16x8 vb[8];
#pragma unroll
    for (int i = 0; i < 2; ++i) {
        fa[i][0] = *(const float4*)(pX[i]);
        fa[i][1] = *(const float4*)(pX[i] + 4);
    }
#pragma unroll
    for (int i = 0; i < 8; ++i) vb[i] = *(const bf16x8*)(pB[i]);

    for (int k0 = 0; k0 < D_IN; k0 += 32) {
        __syncthreads();
#pragma unroll
        for (int i = 0; i < 2; ++i) {
            float f[8] = { fa[i][0].x, fa[i][0].y, fa[i][0].z, fa[i][0].w,
                           fa[i][1].x, fa[i][1].y, fa[i][1].z, fa[i][1].w };
            union { bf16x8 v; __hip_bfloat16 h[8]; } u;
#pragma unroll
            for (int q2 = 0; q2 < 8; ++q2) {
                __hip_bfloat16 h = __float2bfloat16(f[q2]);
                u.h[q2] = plane ? __float2bfloat16(f[q2] - __bfloat162float(h)) : h;
            }
            *(bf16x8*)(&As[(w * 16 + i * 8) * 64 + lane * 8]) = u.v;
        }
#pragma unroll
        for (int i = 0; i < 8; ++i)
            *(bf16x8*)(&Bs[i >> 2][(w * 32 + (i & 3) * 8) * 64 + lane * 8]) = vb[i];
        __syncthreads();
        if (k0 + 32 < D_IN) {
#pragma unroll
            for (int i = 0; i < 2; ++i) {
                fa[i][0] = *(const float4*)(pX[i] + k0 + 32);
                fa[i][1] = *(const float4*)(pX[i] + k0 + 36);
            }
#pragma unroll
            for (int i = 0; i < 8; ++i) vb[i] = *(const bf16x8*)(pB[i] + k0 + 32);
        }
        // compute: wave w owns hid cols w*64..w*64+63 (B rows w*64..+63)
        {
            const short* BsT = Bs[w >> 1];
            const int brow0 = (w & 1) * 64;
            bf16x8 ah[4], al[4], bh[4];
#pragma unroll
            for (int i = 0; i < 4; ++i) {
                int r = i * 16 + m15;
                ah[i] = lds_frag(As, r, quad ^ sw);
                al[i] = lds_frag(As, r, (4 + quad) ^ sw);
            }
#pragma unroll
            for (int j = 0; j < 4; ++j)
                bh[j] = lds_frag(BsT, brow0 + j * 16 + m15, quad ^ sw);
#pragma unroll
            for (int i = 0; i < 4; ++i)
#pragma unroll
                for (int j = 0; j < 4; ++j) {
                    floatx4 c = acc1[i][j];
                    c = __builtin_amdgcn_mfma_f32_16x16x32_bf16(ah[i], bh[j], c, 0, 0, 0);
                    c = __builtin_amdgcn_mfma_f32_16x16x32_bf16(al[i], bh[j], c, 0, 0, 0);
                    acc1[i][j] = c;
                }
        }
    }

    // phase-1 epilogue: bias + relu -> Hs[w] (k-tile w), swizzled chunk layout
#pragma unroll
    for (int i = 0; i < 4; ++i) {
#pragma unroll
        for (int j = 0; j < 4; ++j) {
#pragma unroll
            for (int t = 0; t < 4; ++t) {
                int row = i * 16 + quad * 4 + t;
                int col = w * 64 + j * 16 + m15;          // hid col = phase-2 k
                float v = acc1[i][j][t] + b1eff[(size_t)e * HID + col];
                v = fmaxf(v, 0.f);
                __hip_bfloat16 hb = __float2bfloat16(v);
                int kin = col & 63;
                int pos = (kin >> 3) ^ (row & 7);
                Hs[w][row * 64 + pos * 8 + (kin & 7)] = *(short*)&hb;
            }
        }
    }
    __syncthreads();

    // ---------------- phase 2 ----------------
    // out[64][1024] = hid @ W2t[e]^T.  A resident in Hs; B staged per
    // (col-chunk, K-step) into Bs[0]. 8 col-chunks x 4 K-steps of 64.
    const int wm2 = w & 1, wn2 = w >> 1;
    short* Bs2 = Bs[0];
    const int g2 = (lane & 7) ^ lr, kofs2 = g2 * 8;
    floatx4 acc2[2][4];
    bf16x8 vb2[4];
#pragma unroll
    for (int i = 0; i < 4; ++i)
        vb2[i] = *(const bf16x8*)(W2 + (size_t)(w * 32 + i * 8 + lr) * HID + kofs2);

    for (int it = 0; it < 32; ++it) {
        const int c0 = (it >> 2) * 128, ks = it & 3;
        __syncthreads();
#pragma unroll
        for (int i = 0; i < 4; ++i)
            *(bf16x8*)(&Bs2[(w * 32 + i * 8) * 64 + lane * 8]) = vb2[i];
        __syncthreads();
        if (it + 1 < 32) {
            const int nc0 = ((it + 1) >> 2) * 128, nks = (it + 1) & 3;
#pragma unroll
            for (int i = 0; i < 4; ++i)
                vb2[i] = *(const bf16x8*)(W2 + (size_t)(nc0 + w * 32 + i * 8 + lr) * HID
                                          + nks * 64 + kofs2);
        }
        if (ks == 0) {
#pragma unroll
            for (int i = 0; i < 2; ++i)
#pragma unroll
                for (int j = 0; j < 4; ++j) acc2[i][j] = (floatx4)(0.f);
        }
        const short* Ht = Hs[ks];
#pragma unroll
        for (int kk = 0; kk < 2; ++kk) {
            bf16x8 af[2], bfr[4];
#pragma unroll
            for (int i = 0; i < 2; ++i)
                af[i] = lds_frag(Ht, wm2 * 32 + i * 16 + m15, ((kk << 2) + quad) ^ sw);
#pragma unroll
            for (int j = 0; j < 4; ++j)
                bfr[j] = lds_frag(Bs2, wn2 * 64 + j * 16 + m15, ((kk << 2) + quad) ^ sw);
#pragma unroll
            for (int i = 0; i < 2; ++i)
#pragma unroll
                for (int j = 0; j < 4; ++j)
                    acc2[i][j] = __builtin_amdgcn_mfma_f32_16x16x32_bf16(af[i], bfr[j],
                                                                         acc2[i][j], 0, 0, 0);
        }
        if (ks == 3) {
#pragma unroll
            for (int i = 0; i < 2; ++i) {
#pragma unroll
                for (int t = 0; t < 4; ++t) {
                    int row = row0 + wm2 * 32 + i * 16 + quad * 4 + t;
                    size_t rb = (size_t)row * D_OUT;
#pragma unroll
                    for (int j = 0; j < 4; ++j) {
                        int col = c0 + wn2 * 64 + j * 16 + m15;
                        exp_out_[rb + col] = __float2bfloat16(acc2[i][j][t]);
                    }
                }
            }
        }
    }
}

// ---------------------------------------------------------------------------
// R13 gate-only kernel (x planes no longer materialized — expert_fused
// converts during its own staging). One token per wave; atomic-free.
// ---------------------------------------------------------------------------
__global__ __launch_bounds__(256)
void gate_kernel(const float* __restrict__ x, const float* __restrict__ MgT,
                 const float* __restrict__ bgeff,
                 int* __restrict__ route_e, float* __restrict__ route_w)
{
    const int wave = threadIdx.x >> 6, lane = threadIdx.x & 63;
    const int n = blockIdx.x * 4 + wave;
    const float* xrow = x + (size_t)n * D_IN;

    float4 v[4];
#pragma unroll
    for (int it = 0; it < 4; ++it)
        v[it] = *(const float4*)(xrow + it * 256 + lane * 4);

    float p[NEXP];
#pragma unroll
    for (int e = 0; e < NEXP; ++e) p[e] = 0.f;

#pragma unroll
    for (int it = 0; it < 4; ++it) {
        const int d = it * 256 + lane * 4;
#pragma unroll
        for (int e = 0; e < NEXP; ++e) {
            const float4 m = *(const float4*)(MgT + (size_t)e * 1024 + d);
            p[e] += v[it].x * m.x + v[it].y * m.y + v[it].z * m.z + v[it].w * m.w;
        }
    }

#pragma unroll
    for (int e = 0; e < NEXP; ++e) {
        float t = p[e];
        for (int off = 32; off > 0; off >>= 1) t += __shfl_down(t, off);
        p[e] = t;
    }
    if (lane == 0) {
        float lg[NEXP];
#pragma unroll
        for (int e = 0; e < NEXP; ++e) lg[e] = p[e] + bgeff[e];
        int e0 = 0; float v0 = lg[0];
        for (int e = 1; e < NEXP; ++e) if (lg[e] > v0) { v0 = lg[e]; e0 = e; }
        int e1 = -1; float v1 = -3.0e38f;
        for (int e = 0; e < NEXP; ++e) {
            if (e == e0) continue;
            if (lg[e] > v1) { v1 = lg[e]; e1 = e; }
        }
        float w0 = 1.f / (1.f + expf(v1 - v0));   // softmax + top-2 renorm
        float w1 = 1.f - w0;
        route_e[n * 2]     = e0;
        route_e[n * 2 + 1] = e1;
        route_w[n * 2]     = w0;
        route_w[n * 2 + 1] = w1;
    }
}

// ---------------------------------------------------------------------------
// Histogram of route_e into counts[NEXP] (LDS histogram, 640 global atomics).
// ---------------------------------------------------------------------------
__global__ __launch_bounds__(256)
void count_kernel(const int* __restrict__ route_e, int* __restrict__ counts)
{
    __shared__ int h[NEXP];
    if (threadIdx.x < NEXP) h[threadIdx.x] = 0;
    __syncthreads();
    const int i = blockIdx.x * 512 + threadIdx.x;   // 64 blocks * 512 = 32768
    atomicAdd(&h[route_e[i]], 1);
    atomicAdd(&h[route_e[i + 256]], 1);
    __syncthreads();
    if (threadIdx.x < NEXP) atomicAdd(&counts[threadIdx.x], h[threadIdx.x]);
}

// ---------------------------------------------------------------------------
// R13: all five weight conversions merged into ONE launch (flat 8192-block
// grid, per-range decode) — each block does exactly what its old kernel did.
// ---------------------------------------------------------------------------
__device__ __forceinline__ void transpose_body(float (*t)[33], const float* in,
                                               __hip_bfloat16* out_hi,
                                               __hip_bfloat16* out_lo,
                                               int R, int C, int bx, int by, int bz,
                                               int tid)
{
    const size_t zoff = (size_t)bz * R * C;
    in += zoff; out_hi += zoff; if (out_lo) out_lo += zoff;
    const int c0 = bx * 32, r0 = by * 32;
    const int tx = tid & 31, ty = tid >> 5;
#pragma unroll
    for (int i = 0; i < 4; ++i)
        t[ty + i * 8][tx] = in[(size_t)(r0 + ty + i * 8) * C + (c0 + tx)];
    __syncthreads();
#pragma unroll
    for (int i = 0; i < 4; ++i) {
        float v = t[tx][ty + i * 8];
        size_t o = (size_t)(c0 + ty + i * 8) * R + (r0 + tx);
        __hip_bfloat16 hi = __float2bfloat16(v);
        out_hi[o] = hi;
        if (out_lo) out_lo[o] = __float2bfloat16(v - __bfloat162float(hi));
    }
}

__device__ __forceinline__ void plain_body(const float* in, __hip_bfloat16* oh,
                                           __hip_bfloat16* ol, int b, int tid)
{
    const int i = b * 256 + tid;
    const float4 v = ((const float4*)in)[i];
    union { __hip_bfloat16 bb[4]; short4 s; } uh, ul;
    uh.bb[0] = __float2bfloat16(v.x); ul.bb[0] = __float2bfloat16(v.x - __bfloat162float(uh.bb[0]));
    uh.bb[1] = __float2bfloat16(v.y); ul.bb[1] = __float2bfloat16(v.y - __bfloat162float(uh.bb[1]));
    uh.bb[2] = __float2bfloat16(v.z); ul.bb[2] = __float2bfloat16(v.z - __bfloat162float(uh.bb[2]));
    uh.bb[3] = __float2bfloat16(v.w); ul.bb[3] = __float2bfloat16(v.w - __bfloat162float(uh.bb[3]));
    ((short4*)oh)[i] = uh.s;
    ((short4*)ol)[i] = ul.s;
}

__global__ __launch_bounds__(256)
void prep_convert_kernel(const float* __restrict__ Wo, const float* __restrict__ Wv,
                         const float* __restrict__ Wp, const float* __restrict__ W1,
                         const float* __restrict__ W2,
                         __hip_bfloat16* Wot_hi, __hip_bfloat16* Wot_lo,
                         __hip_bfloat16* Wvr_hi, __hip_bfloat16* Wvr_lo,
                         __hip_bfloat16* Wpr_hi, __hip_bfloat16* Wpr_lo,
                         __hip_bfloat16* W1t, __hip_bfloat16* W1t_lo,
                         __hip_bfloat16* W2t)
{
    __shared__ float t[32][33];
    const int b = blockIdx.x, tid = threadIdx.x;
    if (b < 1024) {
        transpose_body(t, Wo, Wot_hi, Wot_lo, 1024, 1024, b % 32, b / 32, 0, tid);
    } else if (b < 3584) {                       // W1: grid (8,32,10)
        int c = b - 1024;
        transpose_body(t, W1, W1t, W1t_lo, 1024, 256, c % 8, (c / 8) % 32, c / 256, tid);
    } else if (b < 6144) {                       // W2: grid (32,8,10)
        int c = b - 3584;
        transpose_body(t, W2, W2t, nullptr, 256, 1024, c % 32, (c / 32) % 8, c / 256, tid);
    } else if (b < 7168) {
        plain_body(Wv, Wvr_hi, Wvr_lo, b - 6144, tid);
    } else {
        plain_body(Wp, Wpr_hi, Wpr_lo, b - 7168, tid);
    }
}

// ---------------------------------------------------------------------------
// Folded main-chain bias  beff2[n] = bp@(Wv@Wo)[:,n] + bv@Wo[:,n] + bo[n]
// ---------------------------------------------------------------------------
__global__ __launch_bounds__(256)
void bias2_kernel(const float* __restrict__ bp, const float* __restrict__ bv,
                  const float* __restrict__ bo,
                  const __hip_bfloat16* __restrict__ Pt_hi,
                  const __hip_bfloat16* __restrict__ Pt_lo,
                  const __hip_bfloat16* __restrict__ Wot_hi,
                  const __hip_bfloat16* __restrict__ Wot_lo,
                  float* __restrict__ beff2)
{
    const int wave = threadIdx.x >> 6, lane = threadIdx.x & 63;
    const int n = blockIdx.x * 4 + wave;
    float acc = 0.f;
    for (int k = lane; k < D_MODEL; k += 64) {
        const size_t o = (size_t)n * D_MODEL + k;
        float pt = __bfloat162float(Pt_hi[o]) + __bfloat162float(Pt_lo[o]);
        float wo = __bfloat162float(Wot_hi[o]) + __bfloat162float(Wot_lo[o]);
        acc += bp[k] * pt + bv[k] * wo;
    }
    for (int off = 32; off > 0; off >>= 1) acc += __shfl_down(acc, off);
    if (lane == 0) beff2[n] = acc + bo[n];
}

// ---------------------------------------------------------------------------
// b1eff[e][h] = beff2 @ W1[e][:,h] + b1[e][h], via W1t hi+lo (~fp32).
// ---------------------------------------------------------------------------
__global__ __launch_bounds__(256)
void b1eff_kernel(const float* __restrict__ beff2,
                  const __hip_bfloat16* __restrict__ W1t_hi,
                  const __hip_bfloat16* __restrict__ W1t_lo,
                  const float* __restrict__ b1, float* __restrict__ b1eff)
{
    const int wave = threadIdx.x >> 6, lane = threadIdx.x & 63;
    const int n = blockIdx.x * 4 + wave;     // [0, NEXP*HID)
    const size_t base = (size_t)n * D_MODEL;
    float acc = 0.f;
    for (int k = lane; k < D_MODEL; k += 64)
        acc += beff2[k] * (__bfloat162float(W1t_hi[base + k]) +
                           __bfloat162float(W1t_lo[base + k]));
    for (int off = 32; off > 0; off >>= 1) acc += __shfl_down(acc, off);
    if (lane == 0) b1eff[n] = acc + b1[n];
}

// ---------------------------------------------------------------------------
// Thin fp32 GEMM for gate-matrix chain: Cm = A[1024][1024] @ B[1024][10];
// trans=0 -> Cm[m][10]; trans=1 -> Cm[e][1024] (transposed write for MgT).
// ---------------------------------------------------------------------------
__global__ __launch_bounds__(256)
void wchain_kernel(const float* __restrict__ A, const float* __restrict__ B,
                   float* __restrict__ Cm, int trans)
{
    const int wave = threadIdx.x >> 6, lane = threadIdx.x & 63;
    const int m = blockIdx.x * 4 + wave;
    float acc[NEXP];
#pragma unroll
    for (int e = 0; e < NEXP; ++e) acc[e] = 0.f;
    const float* ar = A + (size_t)m * 1024;
    for (int d = lane; d < 1024; d += 64) {
        float av = ar[d];
        const float* br = B + (size_t)d * NEXP;
#pragma unroll
        for (int e = 0; e < NEXP; ++e) acc[e] += av * br[e];
    }
#pragma unroll
    for (int e = 0; e < NEXP; ++e) {
        float v = acc[e];
        for (int off = 32; off > 0; off >>= 1) v += __shfl_down(v, off);
        if (lane == 0) Cm[trans ? ((size_t)e * 1024 + m) : ((size_t)m * NEXP + e)] = v;
    }
}

// ---------------------------------------------------------------------------
// bg_eff = bg + bo@Wg + bv@t1 + bp@t2    (single block)
// ---------------------------------------------------------------------------
__global__ __launch_bounds__(256)
void bias_eff_kernel(const float* __restrict__ bp, const float* __restrict__ bv,
                     const float* __restrict__ bo, const float* __restrict__ bg,
                     const float* __restrict__ Wg, const float* __restrict__ t1,
                     const float* __restrict__ t2, float* __restrict__ bgeff)
{
    __shared__ float red[256];
    const int tid = threadIdx.x;
    float acc[NEXP];
#pragma unroll
    for (int e = 0; e < NEXP; ++e) acc[e] = 0.f;
    for (int d = tid; d < 1024; d += 256) {
        float o = bo[d], v = bv[d], p = bp[d];
#pragma unroll
        for (int e = 0; e < NEXP; ++e)
            acc[e] += o * Wg[d * NEXP + e] + v * t1[d * NEXP + e] + p * t2[d * NEXP + e];
    }
    for (int e = 0; e < NEXP; ++e) {
        red[tid] = acc[e];
        __syncthreads();
        for (int s = 128; s > 0; s >>= 1) {
            if (tid < s) red[tid] += red[tid + s];
            __syncthreads();
        }
        if (tid == 0) bgeff[e] = red[0] + bg[e];
        __syncthreads();
    }
}

// ---------------------------------------------------------------------------
__global__ __launch_bounds__(256)
void init_kernel(int* __restrict__ counts, int* __restrict__ cursors,
                 int* __restrict__ assign_token, float* __restrict__ fzero)
{
    int i = blockIdx.x * 256 + threadIdx.x;
    if (i < NEXP) { counts[i] = 0; cursors[i] = 0; }
    if (i < 1024) fzero[i] = 0.f;               // fp32 zero row (bias + gather pad)
    if (i < A_CAP) assign_token[i] = -1;
}

__global__ void offsets_kernel(const int* __restrict__ counts, int* __restrict__ offs)
{
    if (threadIdx.x == 0 && blockIdx.x == 0) {
        int acc = 0;
        for (int e = 0; e < NEXP; ++e) {
            offs[e] = acc;
            acc += (counts[e] + EPAD - 1) / EPAD * EPAD;
        }
        offs[NEXP] = acc;
    }
}

// ---------------------------------------------------------------------------
// Scatter with WAVE-AGGREGATED cursor atomics (R6).
// ---------------------------------------------------------------------------
__global__ __launch_bounds__(256)
void scatter_kernel(const int* __restrict__ route_e,
                    const int* __restrict__ offs, int* __restrict__ cursors,
                    int* __restrict__ assign_token, int* __restrict__ slot_of)
{
    const int i = blockIdx.x * 256 + threadIdx.x;
    const int lane = threadIdx.x & 63;
    const int e = route_e[i];
    int slot = 0;
#pragma unroll
    for (int q = 0; q < NEXP; ++q) {
        unsigned long long mask = __ballot(e == q);
        if (e == q) {
            const int leader = (int)__ffsll((long long)mask) - 1;
            const int rank = (int)__popcll(mask & ((1ull << lane) - 1ull));
            int base = 0;
            if (lane == leader) base = atomicAdd(&cursors[q], (int)__popcll(mask));
            base = __shfl(base, leader);
            slot = offs[q] + base + rank;
        }
    }
    assign_token[slot] = i >> 1;
    slot_of[i] = slot;
}

// ---------------------------------------------------------------------------
// Combine (gather): out[n] = w0*(row(s0)+b2[e0]) + w1*(row(s1)+b2[e1])
// ---------------------------------------------------------------------------
__global__ __launch_bounds__(256)
void combine_kernel(const __hip_bfloat16* __restrict__ exp_out,
                    const int* __restrict__ slot_of, const int* __restrict__ route_e,
                    const float* __restrict__ route_w, const float* __restrict__ b2,
                    float* __restrict__ out)
{
    const int n = blockIdx.x;
    const int c = threadIdx.x * 4;
    const int s0 = slot_of[n * 2],  s1 = slot_of[n * 2 + 1];
    const int e0 = route_e[n * 2],  e1 = route_e[n * 2 + 1];
    const float w0 = route_w[n * 2], w1 = route_w[n * 2 + 1];

    union U { float2 f2; __hip_bfloat16 b[4]; } u0, u1;
    u0.f2 = *(const float2*)(exp_out + (size_t)s0 * D_OUT + c);
    u1.f2 = *(const float2*)(exp_out + (size_t)s1 * D_OUT + c);
    const float4 bb0 = *(const float4*)(b2 + (size_t)e0 * D_OUT + c);
    const float4 bb1 = *(const float4*)(b2 + (size_t)e1 * D_OUT + c);

    float4 o;
    o.x = w0 * (__bfloat162float(u0.b[0]) + bb0.x) + w1 * (__bfloat162float(u1.b[0]) + bb1.x);
    o.y = w0 * (__bfloat162float(u0.b[1]) + bb0.y) + w1 * (__bfloat162float(u1.b[1]) + bb1.y);
    o.z = w0 * (__bfloat162float(u0.b[2]) + bb0.z) + w1 * (__bfloat162float(u1.b[2]) + bb1.z);
    o.w = w0 * (__bfloat162float(u0.b[3]) + bb0.w) + w1 * (__bfloat162float(u1.b[3]) + bb1.w);
    *(float4*)(out + (size_t)n * D_OUT + c) = o;
}

// ---------------------------------------------------------------------------
extern "C" void kernel_launch(void* const* d_in, const int* in_sizes, int n_in,
                              void* d_out, int out_size, void* d_ws, size_t ws_size,
                              hipStream_t stream)
{
    const float* x  = (const float*)d_in[0];
    const float* Wp = (const float*)d_in[2];
    const float* bp = (const float*)d_in[3];
    const float* Wv = (const float*)d_in[4];
    const float* bv = (const float*)d_in[5];
    const float* Wo = (const float*)d_in[6];
    const float* bo = (const float*)d_in[7];
    const float* Wg = (const float*)d_in[8];
    const float* bg = (const float*)d_in[9];
    const float* W1 = (const float*)d_in[10];
    const float* b1 = (const float*)d_in[11];
    const float* W2 = (const float*)d_in[12];
    const float* b2 = (const float*)d_in[13];
    float* out = (float*)d_out;

    // ---- workspace layout (bytes); lifetime-based aliasing ----
    // R13: x planes and hid GONE (expert_fused gathers fp32 x directly and
    // keeps hid in LDS). exp_out owns region 0..69.7MB exclusively.
    char* W = (char*)d_ws;
    typedef __hip_bfloat16 bf;
    bf* exp_out = (bf*)(W + 0);                // [A_CAP,D_OUT] 69.7MB
    // weight-product scratch (88..100MB)
    bf* Wvr_hi = (bf*)(W + 88080384);          // Wv row-major hi/lo
    bf* Wvr_lo = (bf*)(W + 90177536);
    bf* Wpr_hi = (bf*)(W + 92274688);          // Wp row-major hi/lo
    bf* Wpr_lo = (bf*)(W + 94371840);
    float* fzero = (float*)(W + 96468992);     // 1024 fp32 zeros (bias + zero row)
    float* beff2 = (float*)(W + 96473088);     // folded main-chain bias [1024]
    // (100..117MB)
    bf* W1t_lo   = (bf*)(W + 100663296);       // [E][HID][D] lo plane
    bf* W1eff_hi = (bf*)(W + 105906176);       // (M@W1[e])^T hi  [E][HID][D_IN]
    float* b1eff = (float*)(W + 116391936);    // [E][HID] fp32
    // weights / products (alive whole run)
    bf* Pt_hi  = (bf*)(W + 134217728);         // (Wv@Wo)^T hi/lo
    bf* Pt_lo  = (bf*)(W + 136314880);
    bf* Mrow_hi = (bf*)(W + 138412032);        // M = Wp@Wv@Wo ROW-major hi/lo
    bf* Mrow_lo = (bf*)(W + 140509184);
    bf* Wot_hi = (bf*)(W + 142606336);
    bf* Wot_lo = (bf*)(W + 144703488);
    bf* W1t    = (bf*)(W + 146800640);         // [E][HID][D] hi plane
    bf* W2t    = (bf*)(W + 152043520);         // [E][D_OUT][HID]
    // small buffers
    int*   route_e      = (int*)(W + 157288448);
    float* route_w      = (float*)(W + 157419520);
    int*   slot_of      = (int*)(W + 157550592);
    int*   assign_token = (int*)(W + 157681664);
    int*   counts       = (int*)(W + 157817856);
    int*   offs         = (int*)(W + 157817920);
    int*   cursors      = (int*)(W + 157817984);
    float* MgT          = (float*)(W + 157818048);    // [10][1024] transposed
    float* t1           = (float*)(W + 157859008);
    float* t2           = (float*)(W + 157899968);
    float* bgeff        = (float*)(W + 157940928);

    dim3 blk(256);

    // ---- init (fzero used by product passes AND as expert gather pad) ----
    init_kernel<<<(A_CAP + 255) / 256, blk, 0, stream>>>(counts, cursors, assign_token,
                                                         fzero);

    // ---- all weight conversions in ONE launch ----
    prep_convert_kernel<<<8192, blk, 0, stream>>>(Wo, Wv, Wp, W1, W2,
                                                  Wot_hi, Wot_lo, Wvr_hi, Wvr_lo,
                                                  Wpr_hi, Wpr_lo, W1t, W1t_lo, W2t);

    // ---- gate matrix chain (fp32, exactness-preserving associativity) ----
    wchain_kernel<<<256, blk, 0, stream>>>(Wo, Wg, t1, 0);   // t1 = Wo@Wg
    wchain_kernel<<<256, blk, 0, stream>>>(Wv, t1, t2, 0);   // t2 = Wv@t1
    wchain_kernel<<<256, blk, 0, stream>>>(Wp, t2, MgT, 1);  // MgT = (Wp@t2)^T
    bias_eff_kernel<<<1, blk, 0, stream>>>(bp, bv, bo, bg, Wg, t1, t2, bgeff);

    // ---- weight-product passes (split-bf16) ----
    dim3 pgrid(D_MODEL / 128, D_MODEL / 128, 1);   // (8, 8)
    gemm_split_kernel<<<pgrid, blk, 0, stream>>>(Wot_hi, Wot_lo, Wvr_hi, Wvr_lo, fzero,
                                                 Pt_hi, Pt_lo, D_MODEL, D_MODEL, 0, 0, 0);
    gemm_split_kernel<<<pgrid, blk, 0, stream>>>(Wpr_hi, Wpr_lo, Pt_hi, Pt_lo, fzero,
                                                 Mrow_hi, Mrow_lo, D_MODEL, D_MODEL, 0, 0, 0);
    bias2_kernel<<<D_MODEL / 4, blk, 0, stream>>>(bp, bv, bo, Pt_hi, Pt_lo,
                                                  Wot_hi, Wot_lo, beff2);
    b1eff_kernel<<<NEXP * HID / 4, blk, 0, stream>>>(beff2, W1t, W1t_lo, b1, b1eff);
    dim3 wgrid(D_IN / 128, HID / 128, NEXP);       // (8, 2, 10)
    gemm_split_kernel<<<wgrid, blk, 0, stream>>>(W1t, W1t_lo, Mrow_hi, Mrow_lo, fzero,
                                                 W1eff_hi, nullptr, D_MODEL, D_IN,
                                                 (size_t)HID * D_MODEL, 0,
                                                 (size_t)HID * D_IN);

    // ---- gate + count + scatter ----
    gate_kernel<<<N_TOK / 4, blk, 0, stream>>>(x, MgT, bgeff, route_e, route_w);
    count_kernel<<<2 * N_TOK / 512, blk, 0, stream>>>(route_e, counts);
    offsets_kernel<<<1, 64, 0, stream>>>(counts, offs);
    scatter_kernel<<<2 * N_TOK / 256, blk, 0, stream>>>(route_e, offs, cursors,
                                                        assign_token, slot_of);

    // ---- fused experts: both layers, hid in LDS ----
    expert_fused_kernel<<<A_CAP / 64, blk, 0, stream>>>(x, fzero, W1eff_hi, b1eff, W2t,
                                                        assign_token, offs, exp_out);
    combine_kernel<<<N_TOK, blk, 0, stream>>>(exp_out, slot_of, route_e, route_w, b2, out);
}